// Round 1
// baseline (3060.524 us; speedup 1.0000x reference)
//
#include <hip/hip_runtime.h>
#include <math.h>

#define WS 8
#define NH 8
#define C_DIM 64
#define HD 8
#define KS 5
#define EPS 1e-6f

// LDS layout: qkv [192][65] fp32 (m-major, padded), kv[8][8][8], kmean[8][8], sc[64]
__global__ __launch_bounds__(256, 3) void fla_kernel(
    const float* __restrict__ x,        // (8, 64, 256, 256)
    const float* __restrict__ qkv_w,    // (192, 64)
    const float* __restrict__ qkv_b,    // (192,)
    const float* __restrict__ proj_w,   // (64, 64)
    const float* __restrict__ proj_b,   // (64,)
    const float* __restrict__ scale,    // (64,)
    const float* __restrict__ pos_enc,  // (64, 64)
    const float* __restrict__ dwc_w,    // (8, 1, 5, 5)
    const float* __restrict__ dwc_b,    // (8,)
    float* __restrict__ out)            // (8, 64, 256, 256)
{
    __shared__ float qkv_lds[192][65];
    __shared__ float kv_lds[8][8][8];
    __shared__ float kmean_lds[8][8];
    __shared__ float sc_lds[64];

    const int t    = threadIdx.x;
    const int lane = t & 63;
    const int w    = __builtin_amdgcn_readfirstlane(t >> 6);   // wave id, uniform

    const int bid = blockIdx.x;
    const int b   = bid >> 10;
    const int wi  = (bid >> 5) & 31;
    const int wj  = bid & 31;
    const int h0  = wi * 8, w0 = wj * 8;

    if (t < 64) {
        float s = scale[t];
        sc_lds[t] = log1pf(expf(s));      // softplus
    }

    // ---------------- Phase B: load x (lane = token), qkv GEMM ----------------
    const int row = lane >> 3, col = lane & 7;
    const float* xbase = x + (((size_t)b * 64) * 256 + (h0 + row)) * 256 + (w0 + col);
    float xr[64];
    #pragma unroll
    for (int c = 0; c < 64; ++c)
        xr[c] = xbase[(size_t)c * 65536];

    // wave w computes m in [w*48, w*48+48)
    #pragma unroll 1
    for (int mt = 0; mt < 3; ++mt) {
        const int m0 = w * 48 + mt * 16;
        float acc[16];
        #pragma unroll
        for (int mi = 0; mi < 16; ++mi) acc[mi] = qkv_b[m0 + mi];
        #pragma unroll
        for (int mi = 0; mi < 16; ++mi) {
            const float* wrow = qkv_w + (size_t)(m0 + mi) * 64;
            #pragma unroll
            for (int c = 0; c < 64; ++c)
                acc[mi] = fmaf(xr[c], wrow[c], acc[mi]);
        }
        #pragma unroll
        for (int mi = 0; mi < 16; ++mi)
            qkv_lds[m0 + mi][lane] = acc[mi];
    }
    __syncthreads();

    // ---------------- Phase C: transforms. thread = (token n, quarter cq) ----
    const int n  = t >> 2;
    const int cq = t & 3;
    const int c0 = cq * 16;

    float q[16], k[16], v[16];
    #pragma unroll
    for (int j = 0; j < 16; ++j) {
        q[j] = qkv_lds[c0 + j][n];
        k[j] = qkv_lds[64 + c0 + j][n] + pos_enc[n * 64 + c0 + j];
        v[j] = qkv_lds[128 + c0 + j][n];
    }
    float sq = 0.f, sk = 0.f;
    #pragma unroll
    for (int j = 0; j < 16; ++j) {
        float scj = sc_lds[c0 + j];
        q[j] = (fmaxf(q[j], 0.f) + EPS) / scj;
        k[j] = (fmaxf(k[j], 0.f) + EPS) / scj;
        sq += q[j] * q[j];
        sk += k[j] * k[j];
    }
    sq += __shfl_xor(sq, 1); sq += __shfl_xor(sq, 2);
    sk += __shfl_xor(sk, 1); sk += __shfl_xor(sk, 2);
    const float qn = sqrtf(sq), kn = sqrtf(sk);

    float sq3 = 0.f, sk3 = 0.f;
    #pragma unroll
    for (int j = 0; j < 16; ++j) {
        q[j] = q[j] * q[j] * q[j];
        k[j] = k[j] * k[j] * k[j];
        sq3 += q[j] * q[j];
        sk3 += k[j] * k[j];
    }
    sq3 += __shfl_xor(sq3, 1); sq3 += __shfl_xor(sq3, 2);
    sk3 += __shfl_xor(sk3, 1); sk3 += __shfl_xor(sk3, 2);
    const float qs = qn / sqrtf(sq3), ks = kn / sqrtf(sk3);
    #pragma unroll
    for (int j = 0; j < 16; ++j) {
        q[j] *= qs;
        k[j] *= ks;
        qkv_lds[64 + c0 + j][n] = k[j];   // k final back to LDS; v untouched
    }
    __syncthreads();

    // ---------------- Phase D: kv[h][d][e] and kmean[h][d] -------------------
    {
        const int d = lane >> 3, e = lane & 7;
        #pragma unroll
        for (int hh = 0; hh < 2; ++hh) {
            const int h = w + hh * 4;
            float acc = 0.f;
            #pragma unroll
            for (int nn = 0; nn < 64; ++nn)
                acc = fmaf(qkv_lds[64 + h * 8 + d][nn], qkv_lds[128 + h * 8 + e][nn], acc);
            kv_lds[h][d][e] = acc * (1.0f / 64.0f);
        }
        if (w == 0) {
            float acc = 0.f;
            #pragma unroll
            for (int nn = 0; nn < 64; ++nn)
                acc += qkv_lds[64 + (lane >> 3) * 8 + (lane & 7)][nn];
            kmean_lds[lane >> 3][lane & 7] = acc * (1.0f / 64.0f);
        }
    }
    __syncthreads();

    // ---------------- Phase E: attention out + dwc, write out_pre ------------
    const int wsi = n >> 3, wsj = n & 7;
    float outp[16];
    #pragma unroll
    for (int hh = 0; hh < 2; ++hh) {
        const int h = 2 * cq + hh;
        float zden = EPS;
        #pragma unroll
        for (int d = 0; d < 8; ++d)
            zden += q[hh * 8 + d] * kmean_lds[h][d];
        const float z = 1.0f / zden;
        #pragma unroll
        for (int e = 0; e < 8; ++e) {
            float a = 0.f;
            #pragma unroll
            for (int d = 0; d < 8; ++d)
                a = fmaf(q[hh * 8 + d], kv_lds[h][d][e], a);
            outp[hh * 8 + e] = a * z;
        }
    }
    #pragma unroll
    for (int j = 0; j < 16; ++j) {
        const int c = c0 + j;
        const int d = j & 7;                       // c0 multiple of 16 -> c&7 == j&7
        float acc = dwc_b[d];
        #pragma unroll
        for (int u = 0; u < 5; ++u) {
            const int ii = wsi + u - 2;
            #pragma unroll
            for (int vv = 0; vv < 5; ++vv) {
                const int jj = wsj + vv - 2;
                const bool ok = (ii >= 0) & (ii < 8) & (jj >= 0) & (jj < 8);
                const float val = ok ? qkv_lds[128 + c][(ii & 7) * 8 + (jj & 7)] : 0.f;
                acc = fmaf(val, dwc_w[d * 25 + u * 5 + vv], acc);
            }
        }
        outp[j] += acc;
    }
    #pragma unroll
    for (int j = 0; j < 16; ++j)
        qkv_lds[c0 + j][n] = outp[j];             // out_pre into q-slot [c][n]
    __syncthreads();

    // ---------------- Phase F: proj. lane = token, wave w -> co range --------
    {
        const int n2 = lane;
        float facc[16];
        #pragma unroll
        for (int ci = 0; ci < 16; ++ci) facc[ci] = proj_b[w * 16 + ci];
        #pragma unroll
        for (int cb = 0; cb < 4; ++cb) {
            float vin[16];
            #pragma unroll
            for (int cc = 0; cc < 16; ++cc) vin[cc] = qkv_lds[cb * 16 + cc][n2];
            #pragma unroll
            for (int ci = 0; ci < 16; ++ci) {
                const float* prow = proj_w + (size_t)(w * 16 + ci) * 64 + cb * 16;
                #pragma unroll
                for (int cc = 0; cc < 16; ++cc)
                    facc[ci] = fmaf(vin[cc], prow[cc], facc[ci]);
            }
        }
        const int r2 = n2 >> 3, c2 = n2 & 7;
        float* obase = out + (((size_t)b * 64 + w * 16) * 256 + (h0 + r2)) * 256 + (w0 + c2);
        #pragma unroll
        for (int ci = 0; ci < 16; ++ci)
            obase[(size_t)ci * 65536] = facc[ci];
    }
}

extern "C" void kernel_launch(void* const* d_in, const int* in_sizes, int n_in,
                              void* d_out, int out_size, void* d_ws, size_t ws_size,
                              hipStream_t stream) {
    const float* x       = (const float*)d_in[0];
    const float* qkv_w   = (const float*)d_in[1];
    const float* qkv_b   = (const float*)d_in[2];
    const float* proj_w  = (const float*)d_in[3];
    const float* proj_b  = (const float*)d_in[4];
    const float* scale   = (const float*)d_in[5];
    const float* pos_enc = (const float*)d_in[6];
    const float* dwc_w   = (const float*)d_in[7];
    const float* dwc_b   = (const float*)d_in[8];
    float* o = (float*)d_out;

    hipLaunchKernelGGL(fla_kernel, dim3(8192), dim3(256), 0, stream,
                       x, qkv_w, qkv_b, proj_w, proj_b, scale, pos_enc, dwc_w, dwc_b, o);
}